// Round 4
// baseline (71.984 us; speedup 1.0000x reference)
//
#include <hip/hip_runtime.h>

// EmbeddingBag group, fused: 3 tables [10M, 3] fp32, shared indices, B bags.
// out = concat([tile(p0,5), tile(p1,10), tile(p2,6)], axis=0) -> [21B, 3]
//
// One kernel. Each wave handles TWO bags (32 lanes per bag). Gather loop is
// unrolled x2 with all 6 row-loads issued (non-temporal, L1-bypass) before
// accumulation; out-of-range unrolled slots reuse the first index (L2-hit)
// and are nulled via a 0/1 mask FMA -- no divergent load guards.
// Butterfly shfl_xor reduce leaves all 9 sums in every lane; lanes 0..20 of
// each half write all 21 replica rows for their bag.

typedef float f32x3 __attribute__((ext_vector_type(3)));

__device__ __forceinline__ f32x3 nt_row(const float* __restrict__ t, size_t byteoff) {
    const f32x3* p = (const f32x3*)((const char*)t + byteoff);
    return __builtin_nontemporal_load(p);
}

__global__ __launch_bounds__(256) void bag_fused_kernel(
    const int* __restrict__ eb_input,
    const int* __restrict__ eb_offset,
    const float* __restrict__ t0,
    const float* __restrict__ t1,
    const float* __restrict__ t2,
    float* __restrict__ out,
    int N, int B)
{
    const int wid  = (blockIdx.x * blockDim.x + threadIdx.x) >> 6;
    const int lane = threadIdx.x & 63;
    const int l5   = lane & 31;              // lane within half
    const int b    = wid * 2 + (lane >> 5);  // bag id (one per 32-lane half)
    if (b >= B) return;

    const int start = eb_offset[b];
    const int end   = (b + 1 < B) ? eb_offset[b + 1] : N;

    float s0x = 0.f, s0y = 0.f, s0z = 0.f;
    float s1x = 0.f, s1y = 0.f, s1z = 0.f;
    float s2x = 0.f, s2y = 0.f, s2z = 0.f;

    for (int i = start + l5; i < end; i += 64) {
        const int  i2 = i + 32;
        const bool v2 = i2 < end;

        const unsigned idxA = (unsigned)eb_input[i];
        const unsigned idxB = v2 ? (unsigned)eb_input[i2] : idxA;
        const size_t offA = (size_t)(idxA * 12u);
        const size_t offB = (size_t)(idxB * 12u);

        // Issue all 6 independent row gathers before touching any result.
        const f32x3 a0 = nt_row(t0, offA);
        const f32x3 a1 = nt_row(t1, offA);
        const f32x3 a2 = nt_row(t2, offA);
        const f32x3 b0 = nt_row(t0, offB);
        const f32x3 b1 = nt_row(t1, offB);
        const f32x3 b2 = nt_row(t2, offB);

        const float m = v2 ? 1.f : 0.f;

        s0x += a0.x; s0y += a0.y; s0z += a0.z;
        s1x += a1.x; s1y += a1.y; s1z += a1.z;
        s2x += a2.x; s2y += a2.y; s2z += a2.z;

        s0x = fmaf(m, b0.x, s0x); s0y = fmaf(m, b0.y, s0y); s0z = fmaf(m, b0.z, s0z);
        s1x = fmaf(m, b1.x, s1x); s1y = fmaf(m, b1.y, s1y); s1z = fmaf(m, b1.z, s1z);
        s2x = fmaf(m, b2.x, s2x); s2y = fmaf(m, b2.y, s2y); s2z = fmaf(m, b2.z, s2z);
    }

    // Butterfly reduce within each 32-lane half (offsets 16..1 never cross
    // the half boundary). Every lane ends with the full 9 sums for its bag.
#pragma unroll
    for (int off = 16; off > 0; off >>= 1) {
        s0x += __shfl_xor(s0x, off, 64);
        s0y += __shfl_xor(s0y, off, 64);
        s0z += __shfl_xor(s0z, off, 64);
        s1x += __shfl_xor(s1x, off, 64);
        s1y += __shfl_xor(s1y, off, 64);
        s1z += __shfl_xor(s1z, off, 64);
        s2x += __shfl_xor(s2x, off, 64);
        s2y += __shfl_xor(s2y, off, 64);
        s2z += __shfl_xor(s2z, off, 64);
    }

    // Lanes 0..20 of each half write the 21 replica rows for bag b:
    //   rows [0,5B):   tile(p0,5)  -> row l5*B + b, l5 in [0,5)
    //   rows [5B,15B): tile(p1,10) -> row l5*B + b, l5 in [5,15)
    //   rows [15B,21B): tile(p2,6) -> row l5*B + b, l5 in [15,21)
    if (l5 < 21) {
        float x, y, z;
        if (l5 < 5)       { x = s0x; y = s0y; z = s0z; }
        else if (l5 < 15) { x = s1x; y = s1y; z = s1z; }
        else              { x = s2x; y = s2y; z = s2z; }
        float* __restrict__ d = out + ((size_t)l5 * B + b) * 3;
        d[0] = x; d[1] = y; d[2] = z;
    }
}

extern "C" void kernel_launch(void* const* d_in, const int* in_sizes, int n_in,
                              void* d_out, int out_size, void* d_ws, size_t ws_size,
                              hipStream_t stream)
{
    const int*   eb_input  = (const int*)d_in[0];
    const int*   eb_offset = (const int*)d_in[1];
    const float* t0        = (const float*)d_in[2];
    const float* t1        = (const float*)d_in[3];
    const float* t2        = (const float*)d_in[4];
    float*       out       = (float*)d_out;

    const int N = in_sizes[0];   // 819200
    const int B = in_sizes[1];   // 16384

    // 2 bags per wave, 4 waves per block -> 8 bags per block, one full
    // residency round (8192 waves = 32/CU).
    const int waves  = (B + 1) / 2;
    const int blocks = (waves + 3) / 4;
    bag_fused_kernel<<<blocks, 256, 0, stream>>>(eb_input, eb_offset, t0, t1, t2, out, N, B);
}

// Round 5
// 57.708 us; speedup vs baseline: 1.2474x; 1.2474x over previous
//
#include <hip/hip_runtime.h>

// EmbeddingBag group, fused: 3 tables [10M, 3] fp32, shared indices, B bags.
// out = concat([tile(p0,5), tile(p1,10), tile(p2,6)], axis=0) -> [21B, 3]
//
// Single kernel: each wave handles TWO bags (32 lanes per bag, 2 indices per
// lane -> 6 independent row-gathers in flight per lane). Butterfly shfl_xor
// reduce within each 32-lane half leaves all 9 sums in every lane; lanes 0..20
// of each half then write all 21 replica rows for their bag directly.
//
// NOTE (round-4 post-mortem): non-temporal table loads REGRESSED this kernel
// (+21% FETCH_SIZE, +25% time) — the nt bit forfeits L2 dedup of duplicate
// index draws. Keep regular cached loads.

__global__ __launch_bounds__(256) void bag_fused_kernel(
    const int* __restrict__ eb_input,
    const int* __restrict__ eb_offset,
    const float* __restrict__ t0,
    const float* __restrict__ t1,
    const float* __restrict__ t2,
    float* __restrict__ out,
    int N, int B)
{
    const int wid  = (blockIdx.x * blockDim.x + threadIdx.x) >> 6;
    const int lane = threadIdx.x & 63;
    const int l5   = lane & 31;              // lane within half
    const int b    = wid * 2 + (lane >> 5);  // bag id (one per 32-lane half)
    if (b >= B) return;

    const int start = eb_offset[b];
    const int end   = (b + 1 < B) ? eb_offset[b + 1] : N;

    float s0x = 0.f, s0y = 0.f, s0z = 0.f;
    float s1x = 0.f, s1y = 0.f, s1z = 0.f;
    float s2x = 0.f, s2y = 0.f, s2z = 0.f;

    for (int i = start + l5; i < end; i += 32) {
        const unsigned idx = (unsigned)eb_input[i];
        const size_t byteoff = (size_t)(idx * 12u);   // < 120 MB, fits u32
        const float* __restrict__ p0 = (const float*)((const char*)t0 + byteoff);
        const float* __restrict__ p1 = (const float*)((const char*)t1 + byteoff);
        const float* __restrict__ p2 = (const float*)((const char*)t2 + byteoff);
        s0x += p0[0]; s0y += p0[1]; s0z += p0[2];
        s1x += p1[0]; s1y += p1[1]; s1z += p1[2];
        s2x += p2[0]; s2y += p2[1]; s2z += p2[2];
    }

    // Butterfly reduce within each 32-lane half (offsets 16..1 never cross
    // the half boundary). Every lane ends with the full 9 sums for its bag.
#pragma unroll
    for (int off = 16; off > 0; off >>= 1) {
        s0x += __shfl_xor(s0x, off, 64);
        s0y += __shfl_xor(s0y, off, 64);
        s0z += __shfl_xor(s0z, off, 64);
        s1x += __shfl_xor(s1x, off, 64);
        s1y += __shfl_xor(s1y, off, 64);
        s1z += __shfl_xor(s1z, off, 64);
        s2x += __shfl_xor(s2x, off, 64);
        s2y += __shfl_xor(s2y, off, 64);
        s2z += __shfl_xor(s2z, off, 64);
    }

    // Lanes 0..20 of each half write the 21 replica rows for bag b:
    //   rows [0,5B):    tile(p0,5)  -> row l5*B + b, l5 in [0,5)
    //   rows [5B,15B):  tile(p1,10) -> row l5*B + b, l5 in [5,15)
    //   rows [15B,21B): tile(p2,6)  -> row l5*B + b, l5 in [15,21)
    if (l5 < 21) {
        float x, y, z;
        if (l5 < 5)       { x = s0x; y = s0y; z = s0z; }
        else if (l5 < 15) { x = s1x; y = s1y; z = s1z; }
        else              { x = s2x; y = s2y; z = s2z; }
        float* __restrict__ d = out + ((size_t)l5 * B + b) * 3;
        d[0] = x; d[1] = y; d[2] = z;
    }
}

extern "C" void kernel_launch(void* const* d_in, const int* in_sizes, int n_in,
                              void* d_out, int out_size, void* d_ws, size_t ws_size,
                              hipStream_t stream)
{
    const int*   eb_input  = (const int*)d_in[0];
    const int*   eb_offset = (const int*)d_in[1];
    const float* t0        = (const float*)d_in[2];
    const float* t1        = (const float*)d_in[3];
    const float* t2        = (const float*)d_in[4];
    float*       out       = (float*)d_out;

    const int N = in_sizes[0];   // 819200
    const int B = in_sizes[1];   // 16384

    // 2 bags per wave, 4 waves per block -> 8 bags per block, one full
    // residency round (8192 waves = 32/CU).
    const int waves  = (B + 1) / 2;
    const int blocks = (waves + 3) / 4;
    bag_fused_kernel<<<blocks, 256, 0, stream>>>(eb_input, eb_offset, t0, t1, t2, out, N, B);
}